// Round 10
// baseline (270.453 us; speedup 1.0000x reference)
//
#include <hip/hip_runtime.h>
#include <stdint.h>

// MoleculeMultiHeadSelfAttention on MI355X (gfx950), round 10.
// B=2048, N=50, C=256, H=8, D=32.
// - cast_small: Wqk/WaWm/bias/mask/slack (tiny, ~2us)
// - projcast:   proj GEMM (even bids <3200) CONCURRENT with adj/mat bf16 cast
//               (remaining bids, grid-stride) in one launch
// - attn:       r3 wave structure + depth-2 pipeline (S(tj+1) MFMA cluster
//               issued between P-store(tj) and PV(tj)), volatile-LDS ordering,
//               XCD-swizzled grid, setprio around MFMA clusters.

typedef __attribute__((ext_vector_type(8))) short short8;
typedef __attribute__((ext_vector_type(4))) float f32x4;
typedef __attribute__((ext_vector_type(2))) unsigned u32x2;
typedef __attribute__((ext_vector_type(4))) unsigned u32x4;
typedef unsigned short u16;

#define L2E 1.4426950408889634f

__device__ __forceinline__ u16 f2bf(float f) {
  unsigned int u = __float_as_uint(f);
  u = (u + 0x7FFFu + ((u >> 16) & 1u)) >> 16;   // RNE; finite inputs
  return (u16)u;
}
__device__ __forceinline__ unsigned cvt_pk_bf16(float a, float b) {
  unsigned r;
  asm("v_cvt_pk_bf16_f32 %0, %1, %2" : "=v"(r) : "v"(a), "v"(b));
  return r;
}
__device__ __forceinline__ float exp2_fast(float x) {
#if __has_builtin(__builtin_amdgcn_exp2f)
  return __builtin_amdgcn_exp2f(x);
#else
  return __expf(x * 0.6931471805599453f);
#endif
}

// ---------------- tiny casts ----------------
__global__ __launch_bounds__(256) void cast_small(
    const float* __restrict__ Wq, const float* __restrict__ Wk,
    const float* __restrict__ Wa, const float* __restrict__ Wm,
    const float* __restrict__ ba, const float* __restrict__ bm,
    u16* __restrict__ wqk, u16* __restrict__ wab, u16* __restrict__ wmb,
    float* __restrict__ bap, float* __restrict__ bmp, float* __restrict__ maskv,
    u16* __restrict__ qws, u16* __restrict__ kws) {
  const int blk = blockIdx.x, tid = threadIdx.x;
  if (blk < 64) {
    int idx8 = blk * 256 + tid;
    int r = idx8 >> 5, c = (idx8 & 31) * 8;
    const float* src = (r < 256) ? (Wq + (size_t)r * 256 + c)
                                 : (Wk + (size_t)(r - 256) * 256 + c);
    float4 v0 = *(const float4*)(src);
    float4 v1 = *(const float4*)(src + 4);
    short8 o;
    o[0] = f2bf(v0.x); o[1] = f2bf(v0.y); o[2] = f2bf(v0.z); o[3] = f2bf(v0.w);
    o[4] = f2bf(v1.x); o[5] = f2bf(v1.y); o[6] = f2bf(v1.z); o[7] = f2bf(v1.w);
    *(short8*)(wqk + (size_t)idx8 * 8) = o;
  } else if (blk < 168) {
    int idx = (blk - 64) * 256 + tid;
    int r = idx >> 6, c = idx & 63;
    float va = 0.f, vm = 0.f;
    if (r < 400 && c < 50) { va = Wa[r * 50 + c]; vm = Wm[r * 50 + c]; }
    wab[idx] = f2bf(va); wmb[idx] = f2bf(vm);
  } else {
    short8 z = (short8){0,0,0,0,0,0,0,0};
    *(short8*)(qws + (size_t)819200 * 32 + tid * 8) = z;
    *(short8*)(kws + (size_t)819200 * 32 + tid * 8) = z;
#pragma unroll
    for (int j = 0; j < 2; ++j) {
      int idx = tid + 256 * j;
      int hh = idx >> 6, m = idx & 63;
      bap[idx] = (m < 50) ? ba[hh * 50 + m] * L2E : -1.0e30f;
      bmp[idx] = (m < 50) ? bm[hh * 50 + m] * L2E : -1.0e30f;
    }
    if (tid < 64) maskv[tid] = (tid < 50) ? 0.f : -1.0e30f;
  }
}

// ---------------- proj GEMM + adj/mat cast, one launch (grid 3648) ----------------
__global__ __launch_bounds__(256) void projcast_kernel(
    const float* __restrict__ x, const u16* __restrict__ wqk,
    const float* __restrict__ bq, const float* __restrict__ bk,
    u16* __restrict__ qws, u16* __restrict__ kws,
    const float* __restrict__ adj, const float* __restrict__ mat,
    u16* __restrict__ da, u16* __restrict__ dm) {
  __shared__ char xa[64 * 512];
  __shared__ char wb[64 * 512];
  const int bid = blockIdx.x, tid = threadIdx.x;
  const bool isProj = ((bid & 1) == 0) && (bid < 3200);

  if (!isProj) {
    // ---- adj/matrix -> bf16 [102416][64], zero-padded; 2048 workers ----
    int cid = (bid & 1) ? (bid >> 1) : (1824 + ((bid - 3200) >> 1));
    const int total8 = (102416 * 64) / 8;
    for (int i8 = cid * 256 + tid; i8 < total8; i8 += 2048 * 256) {
      int r = i8 >> 3, c = (i8 & 7) * 8;
      short8 oa = (short8){0,0,0,0,0,0,0,0};
      short8 om = (short8){0,0,0,0,0,0,0,0};
      if (r < 102400) {
        size_t base = (size_t)r * 50;
#pragma unroll
        for (int p = 0; p < 4; ++p) {
          int col = c + 2 * p;
          if (col < 50) {
            float2 va = *(const float2*)(adj + base + col);
            float2 vm = *(const float2*)(mat + base + col);
            oa[2*p] = f2bf(va.x); oa[2*p+1] = f2bf(va.y);
            om[2*p] = f2bf(vm.x); om[2*p+1] = f2bf(vm.y);
          }
        }
      }
      *(short8*)(da + (size_t)i8 * 8) = oa;
      *(short8*)(dm + (size_t)i8 * 8) = om;
    }
    return;
  }

  // ---- projection GEMM tile (r3 proj, m0 from bid/2) ----
  const int m0 = (bid >> 1) * 64;
#pragma unroll
  for (int t = 0; t < 16; ++t) {
    int idx = tid + t * 256;
    int r = idx >> 6, c4 = idx & 63;
    float4 v = *(const float4*)(x + (size_t)(m0 + r) * 256 + c4 * 4);
    unsigned long long pk = (unsigned long long)f2bf(v.x)
                          | ((unsigned long long)f2bf(v.y) << 16)
                          | ((unsigned long long)f2bf(v.z) << 32)
                          | ((unsigned long long)f2bf(v.w) << 48);
    int byte = (r * 512 + c4 * 8) ^ ((r & 7) << 4);
    *(unsigned long long*)(xa + byte) = pk;
  }
  __syncthreads();

  const int w = tid >> 6, l = tid & 63, lo = l & 15, g = l >> 4;
  short8 a[8];
  const int ra = 16 * w + lo;
#pragma unroll
  for (int ks = 0; ks < 8; ++ks)
    a[ks] = *(const short8*)(xa + ((ra * 512 + ks * 64 + g * 16) ^ ((ra & 7) << 4)));
  size_t mb[4];
#pragma unroll
  for (int i = 0; i < 4; ++i) {
    int m = m0 + 16 * w + 4 * g + i;
    int b = m / 50;
    int n = m - 50 * b;
    mb[i] = (size_t)b * 12800 + (size_t)n * 32;
  }

  for (int nt = 0; nt < 8; ++nt) {
    __syncthreads();
#pragma unroll
    for (int t = 0; t < 8; ++t) {
      int idx = tid + t * 256;
      int r = idx >> 5, c8 = idx & 31;
      short8 v = *(const short8*)(wqk + (size_t)(nt * 64 + r) * 256 + c8 * 8);
      int byte = (r * 512 + c8 * 16) ^ ((r & 7) << 4);
      *(short8*)(wb + byte) = v;
    }
    __syncthreads();

    f32x4 acc[4];
#pragma unroll
    for (int tj = 0; tj < 4; ++tj) acc[tj] = (f32x4){0.f, 0.f, 0.f, 0.f};
#pragma unroll
    for (int ks = 0; ks < 8; ++ks) {
#pragma unroll
      for (int tj = 0; tj < 4; ++tj) {
        int rb = 16 * tj + lo;
        short8 bb = *(const short8*)(wb + ((rb * 512 + ks * 64 + g * 16) ^ ((rb & 7) << 4)));
        acc[tj] = __builtin_amdgcn_mfma_f32_16x16x32_bf16(a[ks], bb, acc[tj], 0, 0, 0);
      }
    }
    const int n0 = nt * 64;
#pragma unroll
    for (int tj = 0; tj < 4; ++tj) {
      int j = n0 + 16 * tj + lo;
      int jj = j & 255;
      float bias = (j < 256) ? bq[jj] : bk[jj];
      u16* dst = (j < 256) ? qws : kws;
      int hh = jj >> 5, d = jj & 31;
#pragma unroll
      for (int i = 0; i < 4; ++i)
        dst[mb[i] + (size_t)hh * 1600 + d] = f2bf(acc[tj][i] + bias);
    }
  }
}

// ---------------- fused attention (r3 + depth-2 pipeline) ----------------
__device__ __forceinline__ void sm_store(
    f32x4 (&S)[4], const f32x4 (&bml)[4], float sl2e, float lam,
    u16* pb, int buf, int lo, int g) {
  float p[4][4];
#pragma unroll
  for (int ti = 0; ti < 4; ++ti)
#pragma unroll
    for (int i = 0; i < 4; ++i)
      p[ti][i] = exp2_fast(S[ti][i] * sl2e + bml[ti][i]);
  float t0 = (p[0][0] + p[0][1]) + (p[0][2] + p[0][3]);
  float t1 = (p[1][0] + p[1][1]) + (p[1][2] + p[1][3]);
  float t2 = (p[2][0] + p[2][1]) + (p[2][2] + p[2][3]);
  float t3 = (p[3][0] + p[3][1]) + (p[3][2] + p[3][3]);
  float sum = (t0 + t1) + (t2 + t3);
  sum += __shfl_xor(sum, 16);
  sum += __shfl_xor(sum, 32);
  float r = lam * __builtin_amdgcn_rcpf(sum);
#pragma unroll
  for (int ti = 0; ti < 4; ++ti) {
    u32x2 pk;
    pk.x = cvt_pk_bf16(p[ti][0] * r, p[ti][1] * r);
    pk.y = cvt_pk_bf16(p[ti][2] * r, p[ti][3] * r);
    *(volatile u32x2*)(pb + buf * 1152 + lo * 72 + 16 * ti + 4 * g) = pk;
  }
}

__device__ __forceinline__ void pv_acc(
    const u16* pb, int buf, const short8 (&vbS)[2][2], f32x4 (&Otj)[2],
    int lo, int g) {
  __builtin_amdgcn_s_setprio(1);
#pragma unroll
  for (int ks = 0; ks < 2; ++ks) {
    u32x4 t = *(const volatile u32x4*)(pb + buf * 1152 + lo * 72 + ks * 32 + g * 8);
    short8 pa = __builtin_bit_cast(short8, t);
#pragma unroll
    for (int tjv = 0; tjv < 2; ++tjv)
      Otj[tjv] = __builtin_amdgcn_mfma_f32_16x16x32_bf16(pa, vbS[tjv][ks], Otj[tjv], 0, 0, 0);
  }
  __builtin_amdgcn_s_setprio(0);
}

__device__ __forceinline__ void qk_mfma(f32x4 (&S)[4], const short8 (&af)[4], short8 qf) {
  __builtin_amdgcn_s_setprio(1);
#pragma unroll
  for (int ti = 0; ti < 4; ++ti)
    S[ti] = __builtin_amdgcn_mfma_f32_16x16x32_bf16(af[ti], qf,
             (f32x4){0.f, 0.f, 0.f, 0.f}, 0, 0, 0);
  __builtin_amdgcn_s_setprio(0);
}

__device__ __forceinline__ void adjm_mfma(f32x4 (&S)[4], const short8 (&afw)[4][2],
                                          short8 bf0, short8 bf1) {
  __builtin_amdgcn_s_setprio(1);
#pragma unroll
  for (int ti = 0; ti < 4; ++ti)
    S[ti] = __builtin_amdgcn_mfma_f32_16x16x32_bf16(afw[ti][0], bf0,
             (f32x4){0.f, 0.f, 0.f, 0.f}, 0, 0, 0);
#pragma unroll
  for (int ti = 0; ti < 4; ++ti)
    S[ti] = __builtin_amdgcn_mfma_f32_16x16x32_bf16(afw[ti][1], bf1, S[ti], 0, 0, 0);
  __builtin_amdgcn_s_setprio(0);
}

__global__ __launch_bounds__(256) void attn_kernel(
    const u16* __restrict__ qws, const u16* __restrict__ kws,
    const u16* __restrict__ adjb, const u16* __restrict__ matb,
    const u16* __restrict__ wab, const u16* __restrict__ wmb,
    const float* __restrict__ bap, const float* __restrict__ bmp,
    const float* __restrict__ maskv,
    const float* __restrict__ lambdas, float* __restrict__ out) {
  __shared__ u16 smem[4][2304];     // per wave 4608B: kT[32][72] overlaid by P dbuf
  const int tid = threadIdx.x;
  const int w = tid >> 6, l = tid & 63, lo = l & 15, g = l >> 4;
  // XCD-aware bijective swizzle (4096 % 8 == 0): XCD gets contiguous b-range
  const int swz = (blockIdx.x & 7) * 512 + (blockIdx.x >> 3);
  const int bh = swz * 4 + w;
  const int b = bh >> 3, h = bh & 7;
  u16* sh = smem[w];

  // softmax(lambdas[h])
  float la = lambdas[h * 3 + 0], lb = lambdas[h * 3 + 1], lc = lambdas[h * 3 + 2];
  float lmx = fmaxf(la, fmaxf(lb, lc));
  float e0 = __expf(la - lmx), e1 = __expf(lb - lmx), e2 = __expf(lc - lmx);
  float einv = 1.f / (e0 + e1 + e2);
  float lam0 = e0 * einv, lam1 = e1 * einv, lam2 = e2 * einv;

  // stage kT = V^T [32 d][72 m] (volatile writes; rows>=50 finite junk, P=0 masks)
  {
    const u16* kr = kws + (size_t)bh * 1600 + (size_t)l * 32;
#pragma unroll
    for (int ch = 0; ch < 4; ++ch) {
      short8 v = *(const short8*)(kr + ch * 8);
#pragma unroll
      for (int jj = 0; jj < 8; ++jj)
        *(volatile u16*)(sh + (ch * 8 + jj) * 72 + l) = (u16)v[jj];
    }
  }
  short8 vb[2][2];
#pragma unroll
  for (int tjv = 0; tjv < 2; ++tjv)
#pragma unroll
    for (int ks = 0; ks < 2; ++ks) {
      u32x4 t = *(const volatile u32x4*)(sh + (lo + 16 * tjv) * 72 + ks * 32 + g * 8);
      vb[tjv][ks] = __builtin_bit_cast(short8, t);
    }

  f32x4 O[4][2];
#pragma unroll
  for (int tj = 0; tj < 4; ++tj)
#pragma unroll
    for (int tjv = 0; tjv < 2; ++tjv) O[tj][tjv] = (f32x4){0.f, 0.f, 0.f, 0.f};

  // ---- phase 1: S^T = K·Q^T, depth-2 pipelined ----
  {
    const u16* kbase = kws + (size_t)bh * 1600;
    const u16* qbase = qws + (size_t)bh * 1600;
    short8 af[4];
#pragma unroll
    for (int ti = 0; ti < 4; ++ti)
      af[ti] = *(const short8*)(kbase + (size_t)(lo + 16 * ti) * 32 + g * 8);
    f32x4 bml[4];
#pragma unroll
    for (int ti = 0; ti < 4; ++ti)
      bml[ti] = *(const f32x4*)(maskv + 16 * ti + 4 * g);

    f32x4 S[4];
    {
      short8 qf = *(const short8*)(qbase + (size_t)lo * 32 + g * 8);
      qk_mfma(S, af, qf);
    }
#pragma unroll
    for (int tj = 0; tj < 4; ++tj) {
      sm_store(S, bml, 0.0625f * L2E, lam0, sh, tj & 1, lo, g);
      f32x4 Sn[4];
      if (tj < 3) {
        short8 qf = *(const short8*)(qbase + (size_t)(lo + 16 * (tj + 1)) * 32 + g * 8);
        qk_mfma(Sn, af, qf);      // issues between P-store and PV: hides LDS+load lat
      }
      pv_acc(sh, tj & 1, vb, O[tj], lo, g);
      if (tj < 3) {
#pragma unroll
        for (int ti = 0; ti < 4; ++ti) S[ti] = Sn[ti];
      }
    }
  }

  // ---- phases 2 & 3: adj / matrix transforms, depth-2 pipelined ----
#pragma unroll
  for (int ph = 0; ph < 2; ++ph) {
    const u16* aBase = (ph == 0 ? wab : wmb) + (size_t)h * 3200;
    const u16* bBase = (ph == 0 ? adjb : matb) + (size_t)b * 3200;
    const float* bPad = (ph == 0 ? bap : bmp) + h * 64;
    float lamp = (ph == 0) ? lam1 : lam2;

    short8 afw[4][2];
#pragma unroll
    for (int ti = 0; ti < 4; ++ti)
#pragma unroll
      for (int ks = 0; ks < 2; ++ks)
        afw[ti][ks] = *(const short8*)(aBase + (size_t)(lo + 16 * ti) * 64 + ks * 32 + g * 8);
    f32x4 bml[4];
#pragma unroll
    for (int ti = 0; ti < 4; ++ti)
      bml[ti] = *(const f32x4*)(bPad + 16 * ti + 4 * g);

    f32x4 S[4];
    {
      short8 bf0 = *(const short8*)(bBase + (size_t)lo * 64 + g * 8);
      short8 bf1 = *(const short8*)(bBase + (size_t)lo * 64 + 32 + g * 8);
      adjm_mfma(S, afw, bf0, bf1);
    }
#pragma unroll
    for (int tj = 0; tj < 4; ++tj) {
      sm_store(S, bml, L2E, lamp, sh, tj & 1, lo, g);
      f32x4 Sn[4];
      if (tj < 3) {
        int n = lo + 16 * (tj + 1);
        short8 bf0 = *(const short8*)(bBase + (size_t)n * 64 + g * 8);
        short8 bf1 = *(const short8*)(bBase + (size_t)n * 64 + 32 + g * 8);
        adjm_mfma(Sn, afw, bf0, bf1);
      }
      pv_acc(sh, tj & 1, vb, O[tj], lo, g);
      if (tj < 3) {
#pragma unroll
        for (int ti = 0; ti < 4; ++ti) S[ti] = Sn[ti];
      }
    }
  }

  // ---- epilogue: out[b][n][h*32+d], f32 ----
  float* ob = out + (size_t)b * 12800 + h * 32;
#pragma unroll
  for (int tj = 0; tj < 4; ++tj)
#pragma unroll
    for (int i = 0; i < 4; ++i) {
      int n = 16 * tj + 4 * g + i;
      if (n < 50) {
#pragma unroll
        for (int tjv = 0; tjv < 2; ++tjv)
          ob[(size_t)n * 256 + 16 * tjv + lo] = O[tj][tjv][i];
      }
    }
}

extern "C" void kernel_launch(void* const* d_in, const int* in_sizes, int n_in,
                              void* d_out, int out_size, void* d_ws, size_t ws_size,
                              hipStream_t stream) {
  const float* x       = (const float*)d_in[0];
  const float* adj     = (const float*)d_in[1];
  const float* mat     = (const float*)d_in[2];
  const float* Wq      = (const float*)d_in[3];
  const float* bq      = (const float*)d_in[4];
  const float* Wk      = (const float*)d_in[5];
  const float* bk      = (const float*)d_in[6];
  const float* Wa      = (const float*)d_in[7];
  const float* ba      = (const float*)d_in[8];
  const float* Wm      = (const float*)d_in[9];
  const float* bm      = (const float*)d_in[10];
  const float* lambdas = (const float*)d_in[11];
  float* out = (float*)d_out;

  char* ws = (char*)d_ws;
  u16* wqk    = (u16*)ws; ws += (size_t)512 * 256 * 2;
  u16* wab    = (u16*)ws; ws += (size_t)416 * 64 * 2;
  u16* wmb    = (u16*)ws; ws += (size_t)416 * 64 * 2;
  float* bap  = (float*)ws; ws += (size_t)512 * 4;
  float* bmp  = (float*)ws; ws += (size_t)512 * 4;
  float* mskv = (float*)ws; ws += (size_t)64 * 4;
  u16* adjb   = (u16*)ws; ws += (size_t)102416 * 64 * 2;
  u16* matb   = (u16*)ws; ws += (size_t)102416 * 64 * 2;
  u16* qws    = (u16*)ws; ws += (size_t)819264 * 32 * 2;  // 16384*50 + 64 slack
  u16* kws    = (u16*)ws; ws += (size_t)819264 * 32 * 2;

  cast_small<<<169, 256, 0, stream>>>(Wq, Wk, Wa, Wm, ba, bm,
                                      wqk, wab, wmb, bap, bmp, mskv, qws, kws);
  projcast_kernel<<<3648, 256, 0, stream>>>(x, wqk, bq, bk, qws, kws,
                                            adj, mat, adjb, matb);
  attn_kernel<<<4096, 256, 0, stream>>>(qws, kws, adjb, matb, wab, wmb,
                                        bap, bmp, mskv, lambdas, out);
}

// Round 11
// 241.004 us; speedup vs baseline: 1.1222x; 1.1222x over previous
//
#include <hip/hip_runtime.h>
#include <stdint.h>

// MoleculeMultiHeadSelfAttention on MI355X (gfx950), round 11.
// B=2048, N=50, C=256, H=8, D=32.
// EXACT round-3 kernel (best measured: attn 119us, total 204us) with only:
//  (a) volatile-LDS ordering instead of s_waitcnt lgkmcnt(0)+"memory" clobber
//      (removes 12 full drains/wave; correctness proven r7/r8/r10), and
//  (b) XCD-bijective blockIdx swizzle on attn (proven FETCH 88->65MB, free).
// No other diffs: no setprio, no pipelining, no prefetch, cast/proj unchanged.

typedef __attribute__((ext_vector_type(8))) short short8;
typedef __attribute__((ext_vector_type(4))) float f32x4;
typedef __attribute__((ext_vector_type(2))) unsigned u32x2;
typedef __attribute__((ext_vector_type(4))) unsigned u32x4;
typedef unsigned short u16;

#define L2E 1.4426950408889634f

__device__ __forceinline__ u16 f2bf(float f) {
  unsigned int u = __float_as_uint(f);
  u = (u + 0x7FFFu + ((u >> 16) & 1u)) >> 16;   // RNE; finite inputs
  return (u16)u;
}
__device__ __forceinline__ unsigned cvt_pk_bf16(float a, float b) {
  unsigned r;
  asm("v_cvt_pk_bf16_f32 %0, %1, %2" : "=v"(r) : "v"(a), "v"(b));
  return r;
}
__device__ __forceinline__ float exp2_fast(float x) {
#if __has_builtin(__builtin_amdgcn_exp2f)
  return __builtin_amdgcn_exp2f(x);
#else
  return __expf(x * 0.6931471805599453f);
#endif
}

// ---------------- merged casts (one launch; identical to round-3) ----------------
__global__ __launch_bounds__(256) void cast_all(
    const float* __restrict__ adj, const float* __restrict__ mat,
    const float* __restrict__ Wq, const float* __restrict__ Wk,
    const float* __restrict__ Wa, const float* __restrict__ Wm,
    u16* __restrict__ da, u16* __restrict__ dm, u16* __restrict__ wqk,
    u16* __restrict__ wab, u16* __restrict__ wmb,
    u16* __restrict__ qws, u16* __restrict__ kws) {
  const int blk = blockIdx.x, tid = threadIdx.x;
  if (blk < 2048) {
    const int total8 = (102416 * 64) / 8;
    for (int i8 = blk * 256 + tid; i8 < total8; i8 += 2048 * 256) {
      int r = i8 >> 3, c = (i8 & 7) * 8;
      short8 oa = (short8){0,0,0,0,0,0,0,0};
      short8 om = (short8){0,0,0,0,0,0,0,0};
      if (r < 102400) {
        size_t base = (size_t)r * 50;
#pragma unroll
        for (int p = 0; p < 4; ++p) {
          int col = c + 2 * p;
          if (col < 50) {
            float2 va = *(const float2*)(adj + base + col);
            float2 vm = *(const float2*)(mat + base + col);
            oa[2*p] = f2bf(va.x); oa[2*p+1] = f2bf(va.y);
            om[2*p] = f2bf(vm.x); om[2*p+1] = f2bf(vm.y);
          }
        }
      }
      *(short8*)(da + (size_t)i8 * 8) = oa;
      *(short8*)(dm + (size_t)i8 * 8) = om;
    }
  } else if (blk < 2112) {
    int idx8 = (blk - 2048) * 256 + tid;
    int r = idx8 >> 5, c = (idx8 & 31) * 8;
    const float* src = (r < 256) ? (Wq + (size_t)r * 256 + c)
                                 : (Wk + (size_t)(r - 256) * 256 + c);
    float4 v0 = *(const float4*)(src);
    float4 v1 = *(const float4*)(src + 4);
    short8 o;
    o[0] = f2bf(v0.x); o[1] = f2bf(v0.y); o[2] = f2bf(v0.z); o[3] = f2bf(v0.w);
    o[4] = f2bf(v1.x); o[5] = f2bf(v1.y); o[6] = f2bf(v1.z); o[7] = f2bf(v1.w);
    *(short8*)(wqk + (size_t)idx8 * 8) = o;
  } else if (blk < 2216) {
    int idx = (blk - 2112) * 256 + tid;
    int r = idx >> 6, c = idx & 63;
    float va = 0.f, vm = 0.f;
    if (r < 400 && c < 50) { va = Wa[r * 50 + c]; vm = Wm[r * 50 + c]; }
    wab[idx] = f2bf(va); wmb[idx] = f2bf(vm);
  } else {
    short8 z = (short8){0,0,0,0,0,0,0,0};
    *(short8*)(qws + (size_t)819200 * 32 + tid * 8) = z;
    *(short8*)(kws + (size_t)819200 * 32 + tid * 8) = z;
  }
}

// ---------------- projection GEMM (identical to round-3) ----------------
__global__ __launch_bounds__(256) void proj_kernel(
    const float* __restrict__ x, const u16* __restrict__ wqk,
    const float* __restrict__ bq, const float* __restrict__ bk,
    u16* __restrict__ qws, u16* __restrict__ kws) {
  __shared__ char xa[64 * 512];
  __shared__ char wb[64 * 512];
  const int tid = threadIdx.x;
  const int m0 = blockIdx.x * 64;

#pragma unroll
  for (int t = 0; t < 16; ++t) {
    int idx = tid + t * 256;
    int r = idx >> 6, c4 = idx & 63;
    float4 v = *(const float4*)(x + (size_t)(m0 + r) * 256 + c4 * 4);
    unsigned long long pk = (unsigned long long)f2bf(v.x)
                          | ((unsigned long long)f2bf(v.y) << 16)
                          | ((unsigned long long)f2bf(v.z) << 32)
                          | ((unsigned long long)f2bf(v.w) << 48);
    int byte = (r * 512 + c4 * 8) ^ ((r & 7) << 4);
    *(unsigned long long*)(xa + byte) = pk;
  }
  __syncthreads();

  const int w = tid >> 6, l = tid & 63, lo = l & 15, g = l >> 4;
  short8 a[8];
  const int ra = 16 * w + lo;
#pragma unroll
  for (int ks = 0; ks < 8; ++ks)
    a[ks] = *(const short8*)(xa + ((ra * 512 + ks * 64 + g * 16) ^ ((ra & 7) << 4)));
  size_t mb[4];
#pragma unroll
  for (int i = 0; i < 4; ++i) {
    int m = m0 + 16 * w + 4 * g + i;
    int b = m / 50;
    int n = m - 50 * b;
    mb[i] = (size_t)b * 12800 + (size_t)n * 32;
  }

  for (int nt = 0; nt < 8; ++nt) {
    __syncthreads();
#pragma unroll
    for (int t = 0; t < 8; ++t) {
      int idx = tid + t * 256;
      int r = idx >> 5, c8 = idx & 31;
      short8 v = *(const short8*)(wqk + (size_t)(nt * 64 + r) * 256 + c8 * 8);
      int byte = (r * 512 + c8 * 16) ^ ((r & 7) << 4);
      *(short8*)(wb + byte) = v;
    }
    __syncthreads();

    f32x4 acc[4];
#pragma unroll
    for (int tj = 0; tj < 4; ++tj) acc[tj] = (f32x4){0.f, 0.f, 0.f, 0.f};
#pragma unroll
    for (int ks = 0; ks < 8; ++ks) {
#pragma unroll
      for (int tj = 0; tj < 4; ++tj) {
        int rb = 16 * tj + lo;
        short8 bb = *(const short8*)(wb + ((rb * 512 + ks * 64 + g * 16) ^ ((rb & 7) << 4)));
        acc[tj] = __builtin_amdgcn_mfma_f32_16x16x32_bf16(a[ks], bb, acc[tj], 0, 0, 0);
      }
    }
    const int n0 = nt * 64;
#pragma unroll
    for (int tj = 0; tj < 4; ++tj) {
      int j = n0 + 16 * tj + lo;
      int jj = j & 255;
      float bias = (j < 256) ? bq[jj] : bk[jj];
      u16* dst = (j < 256) ? qws : kws;
      int hh = jj >> 5, d = jj & 31;
#pragma unroll
      for (int i = 0; i < 4; ++i)
        dst[mb[i] + (size_t)hh * 1600 + d] = f2bf(acc[tj][i] + bias);
    }
  }
}

// ---------------- fused attention (round-3 structure; volatile-LDS ordering) ----------------
__device__ __forceinline__ void sm_pv_tile(
    f32x4 (&S)[4], const float (&bml)[4][4], float sl2e, float lam,
    u16* pb, const short8 (&vb)[2][2], f32x4 (&Otj)[2], int tj, int lo, int g) {
  float p[4][4];
#pragma unroll
  for (int ti = 0; ti < 4; ++ti)
#pragma unroll
    for (int i = 0; i < 4; ++i)
      p[ti][i] = exp2_fast(S[ti][i] * sl2e + bml[ti][i]);
  float t0 = (p[0][0] + p[0][1]) + (p[0][2] + p[0][3]);
  float t1 = (p[1][0] + p[1][1]) + (p[1][2] + p[1][3]);
  float t2 = (p[2][0] + p[2][1]) + (p[2][2] + p[2][3]);
  float t3 = (p[3][0] + p[3][1]) + (p[3][2] + p[3][3]);
  float sum = (t0 + t1) + (t2 + t3);
  sum += __shfl_xor(sum, 16);
  sum += __shfl_xor(sum, 32);
  float r = lam * __builtin_amdgcn_rcpf(sum);
  // volatile P writes: same-wave DS ops execute in-order in the LDS pipe, so
  // the volatile reads below observe them without any s_waitcnt full drain.
#pragma unroll
  for (int ti = 0; ti < 4; ++ti) {
    u32x2 pk;
    pk.x = cvt_pk_bf16(p[ti][0] * r, p[ti][1] * r);
    pk.y = cvt_pk_bf16(p[ti][2] * r, p[ti][3] * r);
    *(volatile u32x2*)(pb + (tj & 1) * 1152 + lo * 72 + 16 * ti + 4 * g) = pk;
  }
#pragma unroll
  for (int ks = 0; ks < 2; ++ks) {
    u32x4 t = *(const volatile u32x4*)(pb + (tj & 1) * 1152 + lo * 72 + ks * 32 + g * 8);
    short8 pa = __builtin_bit_cast(short8, t);
#pragma unroll
    for (int tjv = 0; tjv < 2; ++tjv)
      Otj[tjv] = __builtin_amdgcn_mfma_f32_16x16x32_bf16(pa, vb[tjv][ks], Otj[tjv], 0, 0, 0);
  }
}

__device__ __forceinline__ void adj_phase(
    const u16* __restrict__ aBase, const u16* __restrict__ bBase,
    const float* __restrict__ biasPtr, float lam,
    u16* pb, const short8 (&vb)[2][2], f32x4 (&O)[4][2], int lo, int g) {
  short8 af[4][2];
#pragma unroll
  for (int ti = 0; ti < 4; ++ti)
#pragma unroll
    for (int ks = 0; ks < 2; ++ks)
      af[ti][ks] = *(const short8*)(aBase + (size_t)(lo + 16 * ti) * 64 + ks * 32 + g * 8);
  float bml[4][4];
#pragma unroll
  for (int ti = 0; ti < 4; ++ti)
#pragma unroll
    for (int i = 0; i < 4; ++i) {
      int m = 16 * ti + 4 * g + i;
      bml[ti][i] = (m < 50) ? biasPtr[m] * L2E : -1.0e30f;
    }
#pragma unroll
  for (int tj = 0; tj < 4; ++tj) {
    short8 bf0 = *(const short8*)(bBase + (size_t)(lo + 16 * tj) * 64 + g * 8);
    short8 bf1 = *(const short8*)(bBase + (size_t)(lo + 16 * tj) * 64 + 32 + g * 8);
    f32x4 S[4];
#pragma unroll
    for (int ti = 0; ti < 4; ++ti) S[ti] = (f32x4){0.f, 0.f, 0.f, 0.f};
#pragma unroll
    for (int ti = 0; ti < 4; ++ti)
      S[ti] = __builtin_amdgcn_mfma_f32_16x16x32_bf16(af[ti][0], bf0, S[ti], 0, 0, 0);
#pragma unroll
    for (int ti = 0; ti < 4; ++ti)
      S[ti] = __builtin_amdgcn_mfma_f32_16x16x32_bf16(af[ti][1], bf1, S[ti], 0, 0, 0);
    sm_pv_tile(S, bml, L2E, lam, pb, vb, O[tj], tj, lo, g);
  }
}

__global__ __launch_bounds__(256) void attn_kernel(
    const u16* __restrict__ qws, const u16* __restrict__ kws,
    const u16* __restrict__ adjb, const u16* __restrict__ matb,
    const u16* __restrict__ wab, const u16* __restrict__ wmb,
    const float* __restrict__ ba, const float* __restrict__ bm,
    const float* __restrict__ lambdas, float* __restrict__ out) {
  __shared__ u16 smem[4][2304];          // per wave 4608B: kT[32][72] then P dbuf
  const int tid = threadIdx.x;
  const int w = tid >> 6, l = tid & 63, lo = l & 15, g = l >> 4;
  // XCD-bijective swizzle (4096 % 8 == 0): each XCD gets a contiguous b-range
  const int swz = (blockIdx.x & 7) * 512 + (blockIdx.x >> 3);
  const int bh = swz * 4 + w;
  const int b = bh >> 3, h = bh & 7;
  u16* sh = smem[w];

  float la = lambdas[h * 3 + 0], lb = lambdas[h * 3 + 1], lc = lambdas[h * 3 + 2];
  float lmx = fmaxf(la, fmaxf(lb, lc));
  float e0 = __expf(la - lmx), e1 = __expf(lb - lmx), e2 = __expf(lc - lmx);
  float einv = 1.f / (e0 + e1 + e2);
  float lam0 = e0 * einv, lam1 = e1 * einv, lam2 = e2 * einv;

  // stage kT = V^T [32 d][72 m], zero pad m>=50 (volatile writes)
  {
    const u16* kr = kws + (size_t)bh * 1600 + (size_t)l * 32;
#pragma unroll
    for (int ch = 0; ch < 4; ++ch) {
      short8 v = (short8){0, 0, 0, 0, 0, 0, 0, 0};
      if (l < 50) v = *(const short8*)(kr + ch * 8);
#pragma unroll
      for (int jj = 0; jj < 8; ++jj)
        *(volatile u16*)(sh + (ch * 8 + jj) * 72 + l) = (u16)v[jj];
    }
  }
  short8 vb[2][2];
#pragma unroll
  for (int tjv = 0; tjv < 2; ++tjv)
#pragma unroll
    for (int ks = 0; ks < 2; ++ks) {
      u32x4 t = *(const volatile u32x4*)(sh + (lo + 16 * tjv) * 72 + ks * 32 + g * 8);
      vb[tjv][ks] = __builtin_bit_cast(short8, t);
    }

  f32x4 O[4][2];
#pragma unroll
  for (int ti = 0; ti < 4; ++ti)
#pragma unroll
    for (int tjv = 0; tjv < 2; ++tjv) O[ti][tjv] = (f32x4){0.f, 0.f, 0.f, 0.f};

  // ---- phase 1: S^T = K·Q^T, scale (1/16)·log2e ----
  {
    short8 af[4];
#pragma unroll
    for (int ti = 0; ti < 4; ++ti)
      af[ti] = *(const short8*)(kws + (size_t)bh * 1600 + (size_t)(lo + 16 * ti) * 32 + g * 8);
    float bml[4][4];
#pragma unroll
    for (int ti = 0; ti < 4; ++ti)
#pragma unroll
      for (int i = 0; i < 4; ++i)
        bml[ti][i] = (16 * ti + 4 * g + i < 50) ? 0.f : -1.0e30f;
#pragma unroll
    for (int tj = 0; tj < 4; ++tj) {
      short8 qf = *(const short8*)(qws + (size_t)bh * 1600 + (size_t)(lo + 16 * tj) * 32 + g * 8);
      f32x4 S[4];
#pragma unroll
      for (int ti = 0; ti < 4; ++ti) S[ti] = (f32x4){0.f, 0.f, 0.f, 0.f};
#pragma unroll
      for (int ti = 0; ti < 4; ++ti)
        S[ti] = __builtin_amdgcn_mfma_f32_16x16x32_bf16(af[ti], qf, S[ti], 0, 0, 0);
      sm_pv_tile(S, bml, 0.0625f * L2E, lam0, sh, vb, O[tj], tj, lo, g);
    }
  }
  // ---- phases 2 & 3 ----
  adj_phase(wab + (size_t)h * 3200, adjb + (size_t)b * 3200, ba + h * 50,
            lam1, sh, vb, O, lo, g);
  adj_phase(wmb + (size_t)h * 3200, matb + (size_t)b * 3200, bm + h * 50,
            lam2, sh, vb, O, lo, g);

  // out[b][n][h*32+d], f32
  float* ob = out + ((size_t)b * 50) * 256 + h * 32;
#pragma unroll
  for (int ti = 0; ti < 4; ++ti)
#pragma unroll
    for (int i = 0; i < 4; ++i) {
      int n = 16 * ti + 4 * g + i;
      if (n < 50) {
#pragma unroll
        for (int tjv = 0; tjv < 2; ++tjv)
          ob[(size_t)n * 256 + 16 * tjv + lo] = O[ti][tjv][i];
      }
    }
}

extern "C" void kernel_launch(void* const* d_in, const int* in_sizes, int n_in,
                              void* d_out, int out_size, void* d_ws, size_t ws_size,
                              hipStream_t stream) {
  const float* x       = (const float*)d_in[0];
  const float* adj     = (const float*)d_in[1];
  const float* mat     = (const float*)d_in[2];
  const float* Wq      = (const float*)d_in[3];
  const float* bq      = (const float*)d_in[4];
  const float* Wk      = (const float*)d_in[5];
  const float* bk      = (const float*)d_in[6];
  const float* Wa      = (const float*)d_in[7];
  const float* ba      = (const float*)d_in[8];
  const float* Wm      = (const float*)d_in[9];
  const float* bm      = (const float*)d_in[10];
  const float* lambdas = (const float*)d_in[11];
  float* out = (float*)d_out;

  char* ws = (char*)d_ws;
  u16* wqk  = (u16*)ws; ws += (size_t)512 * 256 * 2;
  u16* wab  = (u16*)ws; ws += (size_t)416 * 64 * 2;
  u16* wmb  = (u16*)ws; ws += (size_t)416 * 64 * 2;
  u16* adjb = (u16*)ws; ws += (size_t)102416 * 64 * 2;
  u16* matb = (u16*)ws; ws += (size_t)102416 * 64 * 2;
  u16* qws  = (u16*)ws; ws += (size_t)819264 * 32 * 2;   // 16384*50 + 64 slack rows
  u16* kws  = (u16*)ws; ws += (size_t)819264 * 32 * 2;

  cast_all<<<2217, 256, 0, stream>>>(adj, mat, Wq, Wk, Wa, Wm,
                                     adjb, matb, wqk, wab, wmb, qws, kws);
  proj_kernel<<<1600, 256, 0, stream>>>(x, wqk, bq, bk, qws, kws);
  attn_kernel<<<4096, 256, 0, stream>>>(qws, kws, adjb, matb, wab, wmb,
                                        ba, bm, lambdas, out);
}

// Round 12
// 220.722 us; speedup vs baseline: 1.2253x; 1.0919x over previous
//
#include <hip/hip_runtime.h>
#include <stdint.h>

// MoleculeMultiHeadSelfAttention on MI355X (gfx950), round 12 (consolidation).
// B=2048, N=50, C=256, H=8, D=32.
// Byte-exact round-3 structure (best measured: attn 119us / total 204us,
// VGPR 80, lds_fence WITH "memory" clobber, plain LDS ops) plus ONLY the two
// isolated-proven-free additions:
//  (a) XCD-bijective blockIdx swizzle on attn (FETCH 88->65MB, 0 reg cost)
//  (b) pre-scaled(-log2e)/pre-masked bias tables + mask vector (VGPR-neutral
//      in r5/r6) replacing per-lane scalar bias gathers + cndmasks.

typedef __attribute__((ext_vector_type(8))) short short8;
typedef __attribute__((ext_vector_type(4))) float f32x4;
typedef unsigned short u16;

#define L2E 1.4426950408889634f

__device__ __forceinline__ u16 f2bf(float f) {
  unsigned int u = __float_as_uint(f);
  u = (u + 0x7FFFu + ((u >> 16) & 1u)) >> 16;   // RNE; finite inputs
  return (u16)u;
}
__device__ __forceinline__ unsigned cvt_pk_bf16(float a, float b) {
  unsigned r;
  asm("v_cvt_pk_bf16_f32 %0, %1, %2" : "=v"(r) : "v"(a), "v"(b));
  return r;
}
__device__ __forceinline__ float exp2_fast(float x) {
#if __has_builtin(__builtin_amdgcn_exp2f)
  return __builtin_amdgcn_exp2f(x);
#else
  return __expf(x * 0.6931471805599453f);
#endif
}
__device__ __forceinline__ void lds_fence() {
  asm volatile("s_waitcnt lgkmcnt(0)" ::: "memory");   // exact r3 semantics
}

// ---------------- merged casts (one launch) ----------------
__global__ __launch_bounds__(256) void cast_all(
    const float* __restrict__ adj, const float* __restrict__ mat,
    const float* __restrict__ Wq, const float* __restrict__ Wk,
    const float* __restrict__ Wa, const float* __restrict__ Wm,
    const float* __restrict__ ba, const float* __restrict__ bm,
    u16* __restrict__ da, u16* __restrict__ dm, u16* __restrict__ wqk,
    u16* __restrict__ wab, u16* __restrict__ wmb,
    float* __restrict__ bap, float* __restrict__ bmp, float* __restrict__ maskv,
    u16* __restrict__ qws, u16* __restrict__ kws) {
  const int blk = blockIdx.x, tid = threadIdx.x;
  if (blk < 2048) {
    const int total8 = (102416 * 64) / 8;
    for (int i8 = blk * 256 + tid; i8 < total8; i8 += 2048 * 256) {
      int r = i8 >> 3, c = (i8 & 7) * 8;
      short8 oa = (short8){0,0,0,0,0,0,0,0};
      short8 om = (short8){0,0,0,0,0,0,0,0};
      if (r < 102400) {
        size_t base = (size_t)r * 50;
#pragma unroll
        for (int p = 0; p < 4; ++p) {
          int col = c + 2 * p;
          if (col < 50) {
            float2 va = *(const float2*)(adj + base + col);
            float2 vm = *(const float2*)(mat + base + col);
            oa[2*p] = f2bf(va.x); oa[2*p+1] = f2bf(va.y);
            om[2*p] = f2bf(vm.x); om[2*p+1] = f2bf(vm.y);
          }
        }
      }
      *(short8*)(da + (size_t)i8 * 8) = oa;
      *(short8*)(dm + (size_t)i8 * 8) = om;
    }
  } else if (blk < 2112) {
    int idx8 = (blk - 2048) * 256 + tid;
    int r = idx8 >> 5, c = (idx8 & 31) * 8;
    const float* src = (r < 256) ? (Wq + (size_t)r * 256 + c)
                                 : (Wk + (size_t)(r - 256) * 256 + c);
    float4 v0 = *(const float4*)(src);
    float4 v1 = *(const float4*)(src + 4);
    short8 o;
    o[0] = f2bf(v0.x); o[1] = f2bf(v0.y); o[2] = f2bf(v0.z); o[3] = f2bf(v0.w);
    o[4] = f2bf(v1.x); o[5] = f2bf(v1.y); o[6] = f2bf(v1.z); o[7] = f2bf(v1.w);
    *(short8*)(wqk + (size_t)idx8 * 8) = o;
  } else if (blk < 2216) {
    int idx = (blk - 2112) * 256 + tid;
    int r = idx >> 6, c = idx & 63;
    float va = 0.f, vm = 0.f;
    if (r < 400 && c < 50) { va = Wa[r * 50 + c]; vm = Wm[r * 50 + c]; }
    wab[idx] = f2bf(va); wmb[idx] = f2bf(vm);
  } else {
    short8 z = (short8){0,0,0,0,0,0,0,0};
    *(short8*)(qws + (size_t)819200 * 32 + tid * 8) = z;
    *(short8*)(kws + (size_t)819200 * 32 + tid * 8) = z;
#pragma unroll
    for (int j = 0; j < 2; ++j) {
      int idx = tid + 256 * j;          // [0,512)
      int hh = idx >> 6, m = idx & 63;
      bap[idx] = (m < 50) ? ba[hh * 50 + m] * L2E : -1.0e30f;
      bmp[idx] = (m < 50) ? bm[hh * 50 + m] * L2E : -1.0e30f;
    }
    if (tid < 64) maskv[tid] = (tid < 50) ? 0.f : -1.0e30f;
  }
}

// ---------------- projection GEMM (identical to round-3) ----------------
__global__ __launch_bounds__(256) void proj_kernel(
    const float* __restrict__ x, const u16* __restrict__ wqk,
    const float* __restrict__ bq, const float* __restrict__ bk,
    u16* __restrict__ qws, u16* __restrict__ kws) {
  __shared__ char xa[64 * 512];
  __shared__ char wb[64 * 512];
  const int tid = threadIdx.x;
  const int m0 = blockIdx.x * 64;

#pragma unroll
  for (int t = 0; t < 16; ++t) {
    int idx = tid + t * 256;
    int r = idx >> 6, c4 = idx & 63;
    float4 v = *(const float4*)(x + (size_t)(m0 + r) * 256 + c4 * 4);
    unsigned long long pk = (unsigned long long)f2bf(v.x)
                          | ((unsigned long long)f2bf(v.y) << 16)
                          | ((unsigned long long)f2bf(v.z) << 32)
                          | ((unsigned long long)f2bf(v.w) << 48);
    int byte = (r * 512 + c4 * 8) ^ ((r & 7) << 4);
    *(unsigned long long*)(xa + byte) = pk;
  }
  __syncthreads();

  const int w = tid >> 6, l = tid & 63, lo = l & 15, g = l >> 4;
  short8 a[8];
  const int ra = 16 * w + lo;
#pragma unroll
  for (int ks = 0; ks < 8; ++ks)
    a[ks] = *(const short8*)(xa + ((ra * 512 + ks * 64 + g * 16) ^ ((ra & 7) << 4)));
  size_t mb[4];
#pragma unroll
  for (int i = 0; i < 4; ++i) {
    int m = m0 + 16 * w + 4 * g + i;
    int b = m / 50;
    int n = m - 50 * b;
    mb[i] = (size_t)b * 12800 + (size_t)n * 32;
  }

  for (int nt = 0; nt < 8; ++nt) {
    __syncthreads();
#pragma unroll
    for (int t = 0; t < 8; ++t) {
      int idx = tid + t * 256;
      int r = idx >> 5, c8 = idx & 31;
      short8 v = *(const short8*)(wqk + (size_t)(nt * 64 + r) * 256 + c8 * 8);
      int byte = (r * 512 + c8 * 16) ^ ((r & 7) << 4);
      *(short8*)(wb + byte) = v;
    }
    __syncthreads();

    f32x4 acc[4];
#pragma unroll
    for (int tj = 0; tj < 4; ++tj) acc[tj] = (f32x4){0.f, 0.f, 0.f, 0.f};
#pragma unroll
    for (int ks = 0; ks < 8; ++ks) {
#pragma unroll
      for (int tj = 0; tj < 4; ++tj) {
        int rb = 16 * tj + lo;
        short8 bb = *(const short8*)(wb + ((rb * 512 + ks * 64 + g * 16) ^ ((rb & 7) << 4)));
        acc[tj] = __builtin_amdgcn_mfma_f32_16x16x32_bf16(a[ks], bb, acc[tj], 0, 0, 0);
      }
    }
    const int n0 = nt * 64;
#pragma unroll
    for (int tj = 0; tj < 4; ++tj) {
      int j = n0 + 16 * tj + lo;
      int jj = j & 255;
      float bias = (j < 256) ? bq[jj] : bk[jj];
      u16* dst = (j < 256) ? qws : kws;
      int hh = jj >> 5, d = jj & 31;
#pragma unroll
      for (int i = 0; i < 4; ++i)
        dst[mb[i] + (size_t)hh * 1600 + d] = f2bf(acc[tj][i] + bias);
    }
  }
}

// ---------------- fused attention (round-3 structure) ----------------
__device__ __forceinline__ void sm_pv_tile(
    f32x4 (&S)[4], const f32x4 (&bml)[4], float sl2e, float lam,
    u16* pb, const short8 (&vb)[2][2], f32x4 (&Otj)[2], int tj, int lo, int g) {
  float p[4][4];
#pragma unroll
  for (int ti = 0; ti < 4; ++ti)
#pragma unroll
    for (int i = 0; i < 4; ++i)
      p[ti][i] = exp2_fast(S[ti][i] * sl2e + bml[ti][i]);
  float t0 = (p[0][0] + p[0][1]) + (p[0][2] + p[0][3]);
  float t1 = (p[1][0] + p[1][1]) + (p[1][2] + p[1][3]);
  float t2 = (p[2][0] + p[2][1]) + (p[2][2] + p[2][3]);
  float t3 = (p[3][0] + p[3][1]) + (p[3][2] + p[3][3]);
  float sum = (t0 + t1) + (t2 + t3);
  sum += __shfl_xor(sum, 16);
  sum += __shfl_xor(sum, 32);
  float r = lam * __builtin_amdgcn_rcpf(sum);
  u16* base = pb + (tj & 1) * 1152 + lo * 72;
#pragma unroll
  for (int ti = 0; ti < 4; ++ti) {
    uint2 pk;
    pk.x = cvt_pk_bf16(p[ti][0] * r, p[ti][1] * r);
    pk.y = cvt_pk_bf16(p[ti][2] * r, p[ti][3] * r);
    *(uint2*)(base + 16 * ti + 4 * g) = pk;
  }
  lds_fence();
#pragma unroll
  for (int ks = 0; ks < 2; ++ks) {
    short8 pa = *(const short8*)(pb + (tj & 1) * 1152 + lo * 72 + ks * 32 + g * 8);
#pragma unroll
    for (int tjv = 0; tjv < 2; ++tjv)
      Otj[tjv] = __builtin_amdgcn_mfma_f32_16x16x32_bf16(pa, vb[tjv][ks], Otj[tjv], 0, 0, 0);
  }
}

__device__ __forceinline__ void adj_phase(
    const u16* __restrict__ aBase, const u16* __restrict__ bBase,
    const float* __restrict__ bPad, float lam,
    u16* pb, const short8 (&vb)[2][2], f32x4 (&O)[4][2], int lo, int g) {
  short8 af[4][2];
#pragma unroll
  for (int ti = 0; ti < 4; ++ti)
#pragma unroll
    for (int ks = 0; ks < 2; ++ks)
      af[ti][ks] = *(const short8*)(aBase + (size_t)(lo + 16 * ti) * 64 + ks * 32 + g * 8);
  f32x4 bml[4];
#pragma unroll
  for (int ti = 0; ti < 4; ++ti)
    bml[ti] = *(const f32x4*)(bPad + 16 * ti + 4 * g);
#pragma unroll
  for (int tj = 0; tj < 4; ++tj) {
    short8 bf0 = *(const short8*)(bBase + (size_t)(lo + 16 * tj) * 64 + g * 8);
    short8 bf1 = *(const short8*)(bBase + (size_t)(lo + 16 * tj) * 64 + 32 + g * 8);
    f32x4 S[4];
#pragma unroll
    for (int ti = 0; ti < 4; ++ti) S[ti] = (f32x4){0.f, 0.f, 0.f, 0.f};
#pragma unroll
    for (int ti = 0; ti < 4; ++ti)
      S[ti] = __builtin_amdgcn_mfma_f32_16x16x32_bf16(af[ti][0], bf0, S[ti], 0, 0, 0);
#pragma unroll
    for (int ti = 0; ti < 4; ++ti)
      S[ti] = __builtin_amdgcn_mfma_f32_16x16x32_bf16(af[ti][1], bf1, S[ti], 0, 0, 0);
    sm_pv_tile(S, bml, L2E, lam, pb, vb, O[tj], tj, lo, g);
  }
}

__global__ __launch_bounds__(256) void attn_kernel(
    const u16* __restrict__ qws, const u16* __restrict__ kws,
    const u16* __restrict__ adjb, const u16* __restrict__ matb,
    const u16* __restrict__ wab, const u16* __restrict__ wmb,
    const float* __restrict__ bap, const float* __restrict__ bmp,
    const float* __restrict__ maskv,
    const float* __restrict__ lambdas, float* __restrict__ out) {
  __shared__ u16 smem[4][2304];          // per wave 4608B: kT[32][72] then P dbuf
  const int tid = threadIdx.x;
  const int w = tid >> 6, l = tid & 63, lo = l & 15, g = l >> 4;
  // XCD-bijective swizzle (4096 % 8 == 0): each XCD gets a contiguous b-range
  const int swz = (blockIdx.x & 7) * 512 + (blockIdx.x >> 3);
  const int bh = swz * 4 + w;
  const int b = bh >> 3, h = bh & 7;
  u16* sh = smem[w];

  float la = lambdas[h * 3 + 0], lb = lambdas[h * 3 + 1], lc = lambdas[h * 3 + 2];
  float lmx = fmaxf(la, fmaxf(lb, lc));
  float e0 = __expf(la - lmx), e1 = __expf(lb - lmx), e2 = __expf(lc - lmx);
  float einv = 1.f / (e0 + e1 + e2);
  float lam0 = e0 * einv, lam1 = e1 * einv, lam2 = e2 * einv;

  // stage kT = V^T [32 d][72 m], zero pad m>=50
  {
    const u16* kr = kws + (size_t)bh * 1600 + (size_t)l * 32;
#pragma unroll
    for (int ch = 0; ch < 4; ++ch) {
      short8 v = (short8){0, 0, 0, 0, 0, 0, 0, 0};
      if (l < 50) v = *(const short8*)(kr + ch * 8);
#pragma unroll
      for (int jj = 0; jj < 8; ++jj)
        sh[(ch * 8 + jj) * 72 + l] = (u16)v[jj];
    }
  }
  lds_fence();
  short8 vb[2][2];
#pragma unroll
  for (int tjv = 0; tjv < 2; ++tjv)
#pragma unroll
    for (int ks = 0; ks < 2; ++ks)
      vb[tjv][ks] = *(const short8*)(sh + (lo + 16 * tjv) * 72 + ks * 32 + g * 8);

  f32x4 O[4][2];
#pragma unroll
  for (int ti = 0; ti < 4; ++ti)
#pragma unroll
    for (int tjv = 0; tjv < 2; ++tjv) O[ti][tjv] = (f32x4){0.f, 0.f, 0.f, 0.f};

  // ---- phase 1: S^T = K·Q^T, scale (1/16)·log2e ----
  {
    short8 af[4];
#pragma unroll
    for (int ti = 0; ti < 4; ++ti)
      af[ti] = *(const short8*)(kws + (size_t)bh * 1600 + (size_t)(lo + 16 * ti) * 32 + g * 8);
    f32x4 bml[4];
#pragma unroll
    for (int ti = 0; ti < 4; ++ti)
      bml[ti] = *(const f32x4*)(maskv + 16 * ti + 4 * g);
#pragma unroll
    for (int tj = 0; tj < 4; ++tj) {
      short8 qf = *(const short8*)(qws + (size_t)bh * 1600 + (size_t)(lo + 16 * tj) * 32 + g * 8);
      f32x4 S[4];
#pragma unroll
      for (int ti = 0; ti < 4; ++ti) S[ti] = (f32x4){0.f, 0.f, 0.f, 0.f};
#pragma unroll
      for (int ti = 0; ti < 4; ++ti)
        S[ti] = __builtin_amdgcn_mfma_f32_16x16x32_bf16(af[ti], qf, S[ti], 0, 0, 0);
      sm_pv_tile(S, bml, 0.0625f * L2E, lam0, sh, vb, O[tj], tj, lo, g);
    }
  }
  // ---- phases 2 & 3 ----
  adj_phase(wab + (size_t)h * 3200, adjb + (size_t)b * 3200, bap + h * 64,
            lam1, sh, vb, O, lo, g);
  adj_phase(wmb + (size_t)h * 3200, matb + (size_t)b * 3200, bmp + h * 64,
            lam2, sh, vb, O, lo, g);

  // out[b][n][h*32+d], f32
  float* ob = out + ((size_t)b * 50) * 256 + h * 32;
#pragma unroll
  for (int ti = 0; ti < 4; ++ti)
#pragma unroll
    for (int i = 0; i < 4; ++i) {
      int n = 16 * ti + 4 * g + i;
      if (n < 50) {
#pragma unroll
        for (int tjv = 0; tjv < 2; ++tjv)
          ob[(size_t)n * 256 + 16 * tjv + lo] = O[ti][tjv][i];
      }
    }
}

extern "C" void kernel_launch(void* const* d_in, const int* in_sizes, int n_in,
                              void* d_out, int out_size, void* d_ws, size_t ws_size,
                              hipStream_t stream) {
  const float* x       = (const float*)d_in[0];
  const float* adj     = (const float*)d_in[1];
  const float* mat     = (const float*)d_in[2];
  const float* Wq      = (const float*)d_in[3];
  const float* bq      = (const float*)d_in[4];
  const float* Wk      = (const float*)d_in[5];
  const float* bk      = (const float*)d_in[6];
  const float* Wa      = (const float*)d_in[7];
  const float* ba      = (const float*)d_in[8];
  const float* Wm      = (const float*)d_in[9];
  const float* bm      = (const float*)d_in[10];
  const float* lambdas = (const float*)d_in[11];
  float* out = (float*)d_out;

  char* ws = (char*)d_ws;
  u16* wqk    = (u16*)ws; ws += (size_t)512 * 256 * 2;
  u16* wab    = (u16*)ws; ws += (size_t)416 * 64 * 2;
  u16* wmb    = (u16*)ws; ws += (size_t)416 * 64 * 2;
  float* bap  = (float*)ws; ws += (size_t)512 * 4;
  float* bmp  = (float*)ws; ws += (size_t)512 * 4;
  float* mskv = (float*)ws; ws += (size_t)64 * 4;
  u16* adjb   = (u16*)ws; ws += (size_t)102416 * 64 * 2;
  u16* matb   = (u16*)ws; ws += (size_t)102416 * 64 * 2;
  u16* qws    = (u16*)ws; ws += (size_t)819264 * 32 * 2;  // 16384*50 + 64 slack
  u16* kws    = (u16*)ws; ws += (size_t)819264 * 32 * 2;

  cast_all<<<2217, 256, 0, stream>>>(adj, mat, Wq, Wk, Wa, Wm, ba, bm,
                                     adjb, matb, wqk, wab, wmb,
                                     bap, bmp, mskv, qws, kws);
  proj_kernel<<<1600, 256, 0, stream>>>(x, wqk, bq, bk, qws, kws);
  attn_kernel<<<4096, 256, 0, stream>>>(qws, kws, adjb, matb, wab, wmb,
                                        bap, bmp, mskv, lambdas, out);
}